// Round 1
// baseline (392.812 us; speedup 1.0000x reference)
//
#include <hip/hip_runtime.h>
#include <math.h>

// ---------------------------------------------------------------------------
// HGCN, 2 layers. Key simplification: softmax over a size-1 axis == 1.0, so
// the attention branch (Wa, ba, leaky_relu) is dead code. Each layer:
//   Y = X @ W + b;  agg[n] = -|curv| * (Y[n] + sum_{dst(e)=n} Y[src(e)])
// layer1 -> relu, layer2 -> log_softmax(axis=1).
// Edges are counting-sorted by dst once (same graph both layers), then the
// segment sum is a pure gather (no float atomics).
// ---------------------------------------------------------------------------

// ---------------- GEMM: Y[r][c] = sum_k X[r][k]*W[k][c] + B[c], IC=128 -----
template<int OC>
__launch_bounds__(256)
__global__ void gemm_bias_kernel(const float* __restrict__ X,
                                 const float* __restrict__ W,
                                 const float* __restrict__ B,
                                 float* __restrict__ Y,
                                 int nrows) {
    constexpr int IC = 128;
    constexpr int CG = OC / 4;        // col groups (float4 per thread)
    constexpr int RG = 256 / CG;      // row groups
    constexpr int RPT = 128 / RG;     // rows per thread
    __shared__ float xs[128][IC];     // 64 KB x-tile

    const int t = threadIdx.x;
    const int rowBase = blockIdx.x * 128;

    // load x tile, fully coalesced float4
    {
        const float4* Xv = (const float4*)(X + (size_t)rowBase * IC);
        float4* xsv = (float4*)&xs[0][0];
#pragma unroll
        for (int i = 0; i < 16; ++i) {
            int f = i * 256 + t;              // float4 index in tile (4096)
            int r = f >> 5;                   // 32 float4 per row
            float4 v = (rowBase + r < nrows) ? Xv[f] : make_float4(0.f,0.f,0.f,0.f);
            xsv[f] = v;
        }
    }
    __syncthreads();

    const int cg = t % CG, rg = t / CG;
    const int c0 = cg * 4;
    const int r0 = rg * RPT;

    float4 acc[RPT];
#pragma unroll
    for (int r = 0; r < RPT; ++r) acc[r] = make_float4(0.f,0.f,0.f,0.f);

    for (int k = 0; k < IC; k += 4) {
        float4 w0 = *(const float4*)&W[(k+0)*OC + c0];
        float4 w1 = *(const float4*)&W[(k+1)*OC + c0];
        float4 w2 = *(const float4*)&W[(k+2)*OC + c0];
        float4 w3 = *(const float4*)&W[(k+3)*OC + c0];
#pragma unroll
        for (int r = 0; r < RPT; ++r) {
            float4 xv = *(const float4*)&xs[r0 + r][k];
            acc[r].x = fmaf(xv.w, w3.x, fmaf(xv.z, w2.x, fmaf(xv.y, w1.x, fmaf(xv.x, w0.x, acc[r].x))));
            acc[r].y = fmaf(xv.w, w3.y, fmaf(xv.z, w2.y, fmaf(xv.y, w1.y, fmaf(xv.x, w0.y, acc[r].y))));
            acc[r].z = fmaf(xv.w, w3.z, fmaf(xv.z, w2.z, fmaf(xv.y, w1.z, fmaf(xv.x, w0.z, acc[r].z))));
            acc[r].w = fmaf(xv.w, w3.w, fmaf(xv.z, w2.w, fmaf(xv.y, w1.w, fmaf(xv.x, w0.w, acc[r].w))));
        }
    }

    const float4 bv = *(const float4*)&B[c0];
#pragma unroll
    for (int r = 0; r < RPT; ++r) {
        int row = rowBase + r0 + r;
        if (row < nrows) {
            float4 o = make_float4(acc[r].x + bv.x, acc[r].y + bv.y,
                                   acc[r].z + bv.z, acc[r].w + bv.w);
            *(float4*)&Y[(size_t)row * OC + c0] = o;
        }
    }
}

// ---------------- counting sort of edges by dst ----------------------------
__global__ void hist_kernel(const int* __restrict__ dst, int* __restrict__ deg, int E) {
    int i = blockIdx.x * blockDim.x + threadIdx.x;
    if (i < E) atomicAdd(&deg[dst[i]], 1);
}

__global__ void scatter_kernel(const int* __restrict__ src, const int* __restrict__ dst,
                               int* __restrict__ cursor, int* __restrict__ ssrc, int E) {
    int i = blockIdx.x * blockDim.x + threadIdx.x;
    if (i < E) {
        int d = dst[i];
        int p = atomicAdd(&cursor[d], 1);
        ssrc[p] = src[i];
    }
}

// single-block exclusive scan over n=50000 bins
__launch_bounds__(1024)
__global__ void scan_kernel(const int* __restrict__ deg, int* __restrict__ offs,
                            int* __restrict__ cursor, int n) {
    __shared__ int wsums[16];
    __shared__ int carry_s;
    const int t = threadIdx.x, lane = t & 63, wid = t >> 6;
    if (t == 0) carry_s = 0;
    __syncthreads();
    for (int base = 0; base < n; base += 1024) {
        int i = base + t;
        int v = (i < n) ? deg[i] : 0;
        int incl = v;
#pragma unroll
        for (int d = 1; d < 64; d <<= 1) {
            int tmp = __shfl_up(incl, d);
            if (lane >= d) incl += tmp;
        }
        if (lane == 63) wsums[wid] = incl;
        __syncthreads();
        if (wid == 0) {
            int wv = (lane < 16) ? wsums[lane] : 0;
            int wincl = wv;
#pragma unroll
            for (int d = 1; d < 16; d <<= 1) {
                int tmp = __shfl_up(wincl, d);
                if (lane >= d) wincl += tmp;
            }
            if (lane < 16) wsums[lane] = wincl - wv;   // exclusive wave offsets
        }
        __syncthreads();
        int carry = carry_s;
        int excl = carry + wsums[wid] + incl - v;
        if (i < n) { offs[i] = excl; cursor[i] = excl; }
        __syncthreads();                 // all reads of carry_s done
        if (t == 1023) carry_s = carry + wsums[15] + incl;
        __syncthreads();
    }
    if (t == 0) offs[n] = carry_s;
}

// ---------------- aggregation: one wave per node ---------------------------
// MODE 0: relu(out)      (D==128, float2 per lane)
// MODE 1: log_softmax    (D==64, 1 float per lane, wave shuffle reduce)
template<int D, int MODE>
__launch_bounds__(256)
__global__ void agg_kernel(const float* __restrict__ Y,
                           const int* __restrict__ offs,
                           const int* __restrict__ ssrc,
                           const float* __restrict__ curv,
                           float* __restrict__ out,
                           int nnodes) {
    const int wid = threadIdx.x >> 6;
    const int lane = threadIdx.x & 63;
    const int node = blockIdx.x * 4 + wid;
    if (node >= nnodes) return;

    float a0, a1 = 0.f;
    if constexpr (D == 128) {
        float2 v = *(const float2*)(Y + (size_t)node * D + 2 * lane);
        a0 = v.x; a1 = v.y;
    } else {
        a0 = Y[(size_t)node * D + lane];
    }

    const int s0 = offs[node], s1 = offs[node + 1];
    int j = s0;
    for (; j + 1 < s1; j += 2) {
        int sA = ssrc[j], sB = ssrc[j + 1];
        const float* rA = Y + (size_t)sA * D;
        const float* rB = Y + (size_t)sB * D;
        if constexpr (D == 128) {
            float2 vA = *(const float2*)(rA + 2 * lane);
            float2 vB = *(const float2*)(rB + 2 * lane);
            a0 += vA.x + vB.x; a1 += vA.y + vB.y;
        } else {
            a0 += rA[lane] + rB[lane];
        }
    }
    if (j < s1) {
        int sA = ssrc[j];
        const float* rA = Y + (size_t)sA * D;
        if constexpr (D == 128) {
            float2 vA = *(const float2*)(rA + 2 * lane);
            a0 += vA.x; a1 += vA.y;
        } else {
            a0 += rA[lane];
        }
    }

    const float scale = -fabsf(curv[0]);
    a0 *= scale; a1 *= scale;

    if constexpr (MODE == 0) {
        a0 = fmaxf(a0, 0.f); a1 = fmaxf(a1, 0.f);
        if constexpr (D == 128) {
            *(float2*)(out + (size_t)node * D + 2 * lane) = make_float2(a0, a1);
        } else {
            out[(size_t)node * D + lane] = a0;
        }
    } else {
        // D == 64: log-softmax across the wave's 64 lanes
        float m = a0;
#pragma unroll
        for (int d = 32; d; d >>= 1) m = fmaxf(m, __shfl_xor(m, d));
        float e = expf(a0 - m);
        float s = e;
#pragma unroll
        for (int d = 32; d; d >>= 1) s += __shfl_xor(s, d);
        out[(size_t)node * D + lane] = a0 - m - logf(s);
    }
}

// ---------------------------------------------------------------------------
extern "C" void kernel_launch(void* const* d_in, const int* in_sizes, int n_in,
                              void* d_out, int out_size, void* d_ws, size_t ws_size,
                              hipStream_t stream) {
    const float* x     = (const float*)d_in[0];
    const int*   ei    = (const int*)d_in[1];
    const float* W1    = (const float*)d_in[2];
    const float* b1    = (const float*)d_in[3];
    const float* curv1 = (const float*)d_in[6];
    const float* W2    = (const float*)d_in[7];
    const float* b2    = (const float*)d_in[8];
    const float* curv2 = (const float*)d_in[11];
    float* out = (float*)d_out;

    const int N = 50000;
    const int E = in_sizes[1] / 2;     // 800000
    const int* src = ei;
    const int* dst = ei + E;

    char* ws = (char*)d_ws;
    float* Y1     = (float*)(ws);                        // 25.6 MB (reused as Y2)
    float* h      = (float*)(ws + 26u * 1024 * 1024);    // 25.6 MB
    int*   ssrc   = (int*)  (ws + 52u * 1024 * 1024);    // 3.2 MB
    int*   deg    = (int*)  (ws + 56u * 1024 * 1024);    // 0.2 MB
    int*   offs   = (int*)  (ws + 57u * 1024 * 1024);    // 0.2 MB (N+1)
    int*   cursor = (int*)  (ws + 58u * 1024 * 1024);    // 0.2 MB

    // edge counting sort by dst (graph identical for both layers)
    hipMemsetAsync(deg, 0, N * sizeof(int), stream);
    hist_kernel<<<dim3((E + 255) / 256), dim3(256), 0, stream>>>(dst, deg, E);
    scan_kernel<<<dim3(1), dim3(1024), 0, stream>>>(deg, offs, cursor, N);
    scatter_kernel<<<dim3((E + 255) / 256), dim3(256), 0, stream>>>(src, dst, cursor, ssrc, E);

    // layer 1
    gemm_bias_kernel<128><<<dim3((N + 127) / 128), dim3(256), 0, stream>>>(x, W1, b1, Y1, N);
    agg_kernel<128, 0><<<dim3((N + 3) / 4), dim3(256), 0, stream>>>(Y1, offs, ssrc, curv1, h, N);

    // layer 2 (Y2 aliases Y1 region; Y1 dead after agg1)
    gemm_bias_kernel<64><<<dim3((N + 127) / 128), dim3(256), 0, stream>>>(h, W2, b2, Y1, N);
    agg_kernel<64, 1><<<dim3((N + 3) / 4), dim3(256), 0, stream>>>(Y1, offs, ssrc, curv2, out, N);
}

// Round 2
// 309.928 us; speedup vs baseline: 1.2674x; 1.2674x over previous
//
#include <hip/hip_runtime.h>
#include <math.h>

// ---------------------------------------------------------------------------
// HGCN, 2 layers. softmax over size-1 axis == 1.0 -> attention branch dead.
// Layer: Y = X@W + b (fp32 compute, bf16 store); agg[n] = -|curv| * (Y[n] +
// sum_{dst(e)=n} Y[src(e)]) (bf16 gather, fp32 accumulate).
// layer1 -> relu, layer2 -> log_softmax. CSR built by counting sort
// (hist -> 3-kernel parallel scan -> scatter); gather-based segment sum.
// ---------------------------------------------------------------------------

__device__ inline ushort f2bf(float x) {
    unsigned u = __float_as_uint(x);
    return (ushort)((u + 0x7fffu + ((u >> 16) & 1u)) >> 16);
}
__device__ inline unsigned f2bf_pack(float a, float b) {
    return (unsigned)f2bf(a) | ((unsigned)f2bf(b) << 16);
}
__device__ inline float bflo(unsigned u) { return __uint_as_float(u << 16); }
__device__ inline float bfhi(unsigned u) { return __uint_as_float(u & 0xffff0000u); }

// ---------------- GEMM: Y[r][c] = sum_k X[r][k]*W[k][c] + B[c], IC=128 -----
// output stored bf16-packed (2 cols per uint)
template<int OC>
__launch_bounds__(256)
__global__ void gemm_bias_kernel(const float* __restrict__ X,
                                 const float* __restrict__ W,
                                 const float* __restrict__ B,
                                 unsigned* __restrict__ Yb,
                                 int nrows) {
    constexpr int IC = 128;
    constexpr int CG = OC / 4;        // col groups (4 cols per thread)
    constexpr int RG = 256 / CG;      // row groups
    constexpr int RPT = 128 / RG;     // rows per thread
    __shared__ float xs[128][IC];     // 64 KB x-tile

    const int t = threadIdx.x;
    const int rowBase = blockIdx.x * 128;

    {
        const float4* Xv = (const float4*)(X + (size_t)rowBase * IC);
        float4* xsv = (float4*)&xs[0][0];
#pragma unroll
        for (int i = 0; i < 16; ++i) {
            int f = i * 256 + t;              // float4 index in tile (4096)
            int r = f >> 5;                   // 32 float4 per row
            float4 v = (rowBase + r < nrows) ? Xv[f] : make_float4(0.f,0.f,0.f,0.f);
            xsv[f] = v;
        }
    }
    __syncthreads();

    const int cg = t % CG, rg = t / CG;
    const int c0 = cg * 4;
    const int r0 = rg * RPT;

    float4 acc[RPT];
#pragma unroll
    for (int r = 0; r < RPT; ++r) acc[r] = make_float4(0.f,0.f,0.f,0.f);

    for (int k = 0; k < IC; k += 4) {
        float4 w0 = *(const float4*)&W[(k+0)*OC + c0];
        float4 w1 = *(const float4*)&W[(k+1)*OC + c0];
        float4 w2 = *(const float4*)&W[(k+2)*OC + c0];
        float4 w3 = *(const float4*)&W[(k+3)*OC + c0];
#pragma unroll
        for (int r = 0; r < RPT; ++r) {
            float4 xv = *(const float4*)&xs[r0 + r][k];
            acc[r].x = fmaf(xv.w, w3.x, fmaf(xv.z, w2.x, fmaf(xv.y, w1.x, fmaf(xv.x, w0.x, acc[r].x))));
            acc[r].y = fmaf(xv.w, w3.y, fmaf(xv.z, w2.y, fmaf(xv.y, w1.y, fmaf(xv.x, w0.y, acc[r].y))));
            acc[r].z = fmaf(xv.w, w3.z, fmaf(xv.z, w2.z, fmaf(xv.y, w1.z, fmaf(xv.x, w0.z, acc[r].z))));
            acc[r].w = fmaf(xv.w, w3.w, fmaf(xv.z, w2.w, fmaf(xv.y, w1.w, fmaf(xv.x, w0.w, acc[r].w))));
        }
    }

    const float4 bv = *(const float4*)&B[c0];
#pragma unroll
    for (int r = 0; r < RPT; ++r) {
        int row = rowBase + r0 + r;
        if (row < nrows) {
            uint2 p;
            p.x = f2bf_pack(acc[r].x + bv.x, acc[r].y + bv.y);
            p.y = f2bf_pack(acc[r].z + bv.z, acc[r].w + bv.w);
            *(uint2*)&Yb[(size_t)row * (OC/2) + cg * 2] = p;
        }
    }
}

// ---------------- counting sort of edges by dst ----------------------------
__global__ void hist_kernel(const int* __restrict__ dst, int* __restrict__ deg, int E) {
    int i = blockIdx.x * blockDim.x + threadIdx.x;
    if (i < E) atomicAdd(&deg[dst[i]], 1);
}

__global__ void scatter_kernel(const int* __restrict__ src, const int* __restrict__ dst,
                               int* __restrict__ cursor, int* __restrict__ ssrc, int E) {
    int i = blockIdx.x * blockDim.x + threadIdx.x;
    if (i < E) {
        int d = dst[i];
        int p = atomicAdd(&cursor[d], 1);
        ssrc[p] = src[i];
    }
}

// ---- parallel scan: (1) block partial sums, (2) scan partials, (3) rescan -
__launch_bounds__(256)
__global__ void scan1_kernel(const int* __restrict__ deg, int* __restrict__ bsum, int n) {
    const int t = threadIdx.x;
    const int i0 = blockIdx.x * 1024 + t * 4;
    int s = 0;
#pragma unroll
    for (int k = 0; k < 4; ++k) if (i0 + k < n) s += deg[i0 + k];
#pragma unroll
    for (int d = 32; d; d >>= 1) s += __shfl_xor(s, d);
    __shared__ int ws[4];
    if ((t & 63) == 0) ws[t >> 6] = s;
    __syncthreads();
    if (t == 0) bsum[blockIdx.x] = ws[0] + ws[1] + ws[2] + ws[3];
}

__launch_bounds__(64)
__global__ void scan2_kernel(int* __restrict__ bsum, int* __restrict__ offs, int nb, int n) {
    const int lane = threadIdx.x;
    int v = (lane < nb) ? bsum[lane] : 0;
    int incl = v;
#pragma unroll
    for (int d = 1; d < 64; d <<= 1) {
        int tmp = __shfl_up(incl, d);
        if (lane >= d) incl += tmp;
    }
    if (lane < nb) bsum[lane] = incl - v;     // exclusive
    if (lane == 63) offs[n] = incl;           // total = E
}

__launch_bounds__(256)
__global__ void scan3_kernel(const int* __restrict__ deg, const int* __restrict__ bsum,
                             int* __restrict__ offs, int* __restrict__ cursor, int n) {
    const int t = threadIdx.x;
    const int i0 = blockIdx.x * 1024 + t * 4;
    int v[4];
#pragma unroll
    for (int k = 0; k < 4; ++k) v[k] = (i0 + k < n) ? deg[i0 + k] : 0;
    int tsum = v[0] + v[1] + v[2] + v[3];
    const int lane = t & 63, wid = t >> 6;
    int incl = tsum;
#pragma unroll
    for (int d = 1; d < 64; d <<= 1) {
        int tmp = __shfl_up(incl, d);
        if (lane >= d) incl += tmp;
    }
    __shared__ int ws[4];
    if (lane == 63) ws[wid] = incl;
    __syncthreads();
    int off = bsum[blockIdx.x] + incl - tsum;
    for (int k = 0; k < wid; ++k) off += ws[k];
#pragma unroll
    for (int k = 0; k < 4; ++k) {
        if (i0 + k < n) { offs[i0 + k] = off; cursor[i0 + k] = off; }
        off += v[k];
    }
}

// ---------------- aggregation: one wave per node ---------------------------
// MODE 0: relu, D==128 (uint = 2 bf16 per lane), fp32 out
// MODE 1: log_softmax, D==64 (ushort = 1 bf16 per lane), fp32 out
template<int D, int MODE>
__launch_bounds__(256)
__global__ void agg_kernel(const void* __restrict__ Yv,
                           const int* __restrict__ offs,
                           const int* __restrict__ ssrc,
                           const float* __restrict__ curv,
                           float* __restrict__ out,
                           int nnodes) {
    const int wid = threadIdx.x >> 6;
    const int lane = threadIdx.x & 63;
    const int node = blockIdx.x * 4 + wid;
    if (node >= nnodes) return;

    float a0, a1 = 0.f, b0 = 0.f, b1 = 0.f;
    const unsigned* Yu = (const unsigned*)Yv;
    const ushort* Ys = (const ushort*)Yv;
    if constexpr (D == 128) {
        unsigned u = Yu[(size_t)node * 64 + lane];
        a0 = bflo(u); a1 = bfhi(u);
    } else {
        a0 = __uint_as_float((unsigned)Ys[(size_t)node * 64 + lane] << 16);
    }

    const int s0 = offs[node], s1 = offs[node + 1];
    int j = s0;
    for (; j + 3 < s1; j += 4) {
        int sA = ssrc[j], sB = ssrc[j+1], sC = ssrc[j+2], sD = ssrc[j+3];
        if constexpr (D == 128) {
            unsigned uA = Yu[(size_t)sA * 64 + lane];
            unsigned uB = Yu[(size_t)sB * 64 + lane];
            unsigned uC = Yu[(size_t)sC * 64 + lane];
            unsigned uD = Yu[(size_t)sD * 64 + lane];
            a0 += bflo(uA) + bflo(uB); b0 += bflo(uC) + bflo(uD);
            a1 += bfhi(uA) + bfhi(uB); b1 += bfhi(uC) + bfhi(uD);
        } else {
            float fA = __uint_as_float((unsigned)Ys[(size_t)sA * 64 + lane] << 16);
            float fB = __uint_as_float((unsigned)Ys[(size_t)sB * 64 + lane] << 16);
            float fC = __uint_as_float((unsigned)Ys[(size_t)sC * 64 + lane] << 16);
            float fD = __uint_as_float((unsigned)Ys[(size_t)sD * 64 + lane] << 16);
            a0 += fA + fB; b0 += fC + fD;
        }
    }
    for (; j < s1; ++j) {
        int sA = ssrc[j];
        if constexpr (D == 128) {
            unsigned uA = Yu[(size_t)sA * 64 + lane];
            a0 += bflo(uA); a1 += bfhi(uA);
        } else {
            a0 += __uint_as_float((unsigned)Ys[(size_t)sA * 64 + lane] << 16);
        }
    }
    a0 += b0; a1 += b1;

    const float scale = -fabsf(curv[0]);
    a0 *= scale; a1 *= scale;

    if constexpr (MODE == 0) {
        a0 = fmaxf(a0, 0.f); a1 = fmaxf(a1, 0.f);
        *(float2*)(out + (size_t)node * D + 2 * lane) = make_float2(a0, a1);
    } else {
        float m = a0;
#pragma unroll
        for (int d = 32; d; d >>= 1) m = fmaxf(m, __shfl_xor(m, d));
        float e = expf(a0 - m);
        float s = e;
#pragma unroll
        for (int d = 32; d; d >>= 1) s += __shfl_xor(s, d);
        out[(size_t)node * D + lane] = a0 - m - logf(s);
    }
}

// ---------------------------------------------------------------------------
extern "C" void kernel_launch(void* const* d_in, const int* in_sizes, int n_in,
                              void* d_out, int out_size, void* d_ws, size_t ws_size,
                              hipStream_t stream) {
    const float* x     = (const float*)d_in[0];
    const int*   ei    = (const int*)d_in[1];
    const float* W1    = (const float*)d_in[2];
    const float* b1    = (const float*)d_in[3];
    const float* curv1 = (const float*)d_in[6];
    const float* W2    = (const float*)d_in[7];
    const float* b2    = (const float*)d_in[8];
    const float* curv2 = (const float*)d_in[11];
    float* out = (float*)d_out;

    const int N = 50000;
    const int E = in_sizes[1] / 2;     // 800000
    const int* src = ei;
    const int* dst = ei + E;
    const int NB = (N + 1023) / 1024;  // 49 scan blocks

    char* ws = (char*)d_ws;
    unsigned* Y1b   = (unsigned*)(ws);                       // bf16 [N,128] = 12.8 MB (also Y2b)
    float*    h     = (float*)  (ws + 13u * 1024 * 1024);    // fp32 [N,128] = 25.6 MB
    int*      ssrc  = (int*)    (ws + 40u * 1024 * 1024);    // 3.2 MB
    int*      deg   = (int*)    (ws + 44u * 1024 * 1024);
    int*      offs  = (int*)    (ws + 45u * 1024 * 1024);    // N+1
    int*      cursor= (int*)    (ws + 46u * 1024 * 1024);
    int*      bsum  = (int*)    (ws + 47u * 1024 * 1024);    // NB ints

    // CSR build (graph identical for both layers)
    hipMemsetAsync(deg, 0, N * sizeof(int), stream);
    hist_kernel<<<dim3((E + 255) / 256), dim3(256), 0, stream>>>(dst, deg, E);
    scan1_kernel<<<dim3(NB), dim3(256), 0, stream>>>(deg, bsum, N);
    scan2_kernel<<<dim3(1), dim3(64), 0, stream>>>(bsum, offs, NB, N);
    scan3_kernel<<<dim3(NB), dim3(256), 0, stream>>>(deg, bsum, offs, cursor, N);
    scatter_kernel<<<dim3((E + 255) / 256), dim3(256), 0, stream>>>(src, dst, cursor, ssrc, E);

    // layer 1
    gemm_bias_kernel<128><<<dim3((N + 127) / 128), dim3(256), 0, stream>>>(x, W1, b1, Y1b, N);
    agg_kernel<128, 0><<<dim3((N + 3) / 4), dim3(256), 0, stream>>>(Y1b, offs, ssrc, curv1, h, N);

    // layer 2 (Y2b aliases Y1b; dead after agg1)
    gemm_bias_kernel<64><<<dim3((N + 127) / 128), dim3(256), 0, stream>>>(h, W2, b2, Y1b, N);
    agg_kernel<64, 1><<<dim3((N + 3) / 4), dim3(256), 0, stream>>>(Y1b, offs, ssrc, curv2, out, N);
}

// Round 4
// 243.798 us; speedup vs baseline: 1.6112x; 1.2712x over previous
//
#include <hip/hip_runtime.h>
#include <math.h>

// ---------------------------------------------------------------------------
// HGCN, 2 layers. softmax over size-1 axis == 1.0 -> attention branch dead.
// Layer: Y = X@W + b (bf16 MFMA, fp32 accum, bf16 store);
//        agg[n] = -|curv| * (Y[n] + sum_{dst(e)=n} Y[src(e)]) (bf16 gather).
// layer1 -> relu (bf16 h), layer2 -> log_softmax (fp32 out).
// CSR built via coarse-range counting sort (196 ranges of 256 nodes):
//   histA (LDS hist) -> scanA -> scatterA (packed ldst<<16|src, run-contig
//   writes) -> sortB (per-range exact sort in LDS, emits offs + ssrc).
// ---------------------------------------------------------------------------

#define NRANGE 196            // ceil(50000/256)

typedef float f32x4 __attribute__((ext_vector_type(4)));
typedef short bf16x8 __attribute__((ext_vector_type(8)));

__device__ inline ushort f2bf(float x) {
    unsigned u = __float_as_uint(x);
    return (ushort)((u + 0x7fffu + ((u >> 16) & 1u)) >> 16);
}
__device__ inline unsigned f2bf_pack(float a, float b) {
    return (unsigned)f2bf(a) | ((unsigned)f2bf(b) << 16);
}
__device__ inline float bflo(unsigned u) { return __uint_as_float(u << 16); }
__device__ inline float bfhi(unsigned u) { return __uint_as_float(u & 0xffff0000u); }

// ---------------- weight prep: Wt[c][k] = bf16(W[k][c]) --------------------
__launch_bounds__(256)
__global__ void prep_kernel(const float* __restrict__ W1, const float* __restrict__ W2,
                            ushort* __restrict__ Wt1, ushort* __restrict__ Wt2) {
    int t = blockIdx.x * 256 + threadIdx.x;
    if (t < 16384) {               // 128x128
        int c = t >> 7, k = t & 127;
        Wt1[t] = f2bf(W1[k * 128 + c]);
    } else if (t < 24576) {        // 64x128
        int i = t - 16384;
        int c = i >> 7, k = i & 127;
        Wt2[i] = f2bf(W2[k * 64 + c]);
    }
}

// ---------------- CSR build ------------------------------------------------
__launch_bounds__(256)
__global__ void histA_kernel(const int* __restrict__ dst, int* __restrict__ rangeCnt, int E) {
    __shared__ int h[NRANGE];
    const int t = threadIdx.x;
    if (t < NRANGE) h[t] = 0;
    __syncthreads();
    const int base = blockIdx.x * 4096;
    for (int i = t; i < 4096; i += 256) {
        int e = base + i;
        if (e < E) atomicAdd(&h[dst[e] >> 8], 1);
    }
    __syncthreads();
    if (t < NRANGE && h[t]) atomicAdd(&rangeCnt[t], h[t]);
}

__launch_bounds__(256)
__global__ void scanA_kernel(const int* __restrict__ rangeCnt, int* __restrict__ rangeBase,
                             int* __restrict__ rangeCursor) {
    const int t = threadIdx.x, lane = t & 63, w = t >> 6;
    int v = (t < NRANGE) ? rangeCnt[t] : 0;
    int incl = v;
#pragma unroll
    for (int d = 1; d < 64; d <<= 1) {
        int tmp = __shfl_up(incl, d);
        if (lane >= d) incl += tmp;
    }
    __shared__ int ws[4];
    if (lane == 63) ws[w] = incl;
    __syncthreads();
    int off = 0;
    for (int k = 0; k < w; ++k) off += ws[k];
    int excl = off + incl - v;
    if (t < NRANGE) { rangeBase[t] = excl; rangeCursor[t] = excl; }
    if (t == NRANGE - 1) rangeBase[NRANGE] = excl + v;
}

__launch_bounds__(256)
__global__ void scatterA_kernel(const int* __restrict__ src, const int* __restrict__ dst,
                                int* __restrict__ rangeCursor, unsigned* __restrict__ ebuf, int E) {
    __shared__ int h[NRANGE];
    __shared__ int base[NRANGE];
    const int t = threadIdx.x;
    if (t < NRANGE) h[t] = 0;
    __syncthreads();
    const int cbase = blockIdx.x * 4096;
    for (int i = t; i < 4096; i += 256) {
        int e = cbase + i;
        if (e < E) atomicAdd(&h[dst[e] >> 8], 1);
    }
    __syncthreads();
    if (t < NRANGE) { base[t] = h[t] ? atomicAdd(&rangeCursor[t], h[t]) : 0; h[t] = 0; }
    __syncthreads();
    for (int i = t; i < 4096; i += 256) {
        int e = cbase + i;
        if (e < E) {
            int d = dst[e];
            int r = d >> 8;
            int slot = base[r] + atomicAdd(&h[r], 1);
            ebuf[slot] = (unsigned)src[e] | ((unsigned)(d & 255) << 16);
        }
    }
}

__launch_bounds__(256)
__global__ void sortB_kernel(const unsigned* __restrict__ ebuf, const int* __restrict__ rangeBase,
                             int* __restrict__ offs, int* __restrict__ ssrc, int nnodes) {
    __shared__ int h[256];
    __shared__ int cur[256];
    __shared__ int ws[4];
    const int t = threadIdx.x, lane = t & 63, w = t >> 6;
    const int r = blockIdx.x;
    const int rb = rangeBase[r], re = rangeBase[r + 1];
    h[t] = 0;
    __syncthreads();
    for (int e = rb + t; e < re; e += 256) atomicAdd(&h[ebuf[e] >> 16], 1);
    __syncthreads();
    int v = h[t];
    int incl = v;
#pragma unroll
    for (int d = 1; d < 64; d <<= 1) {
        int tmp = __shfl_up(incl, d);
        if (lane >= d) incl += tmp;
    }
    if (lane == 63) ws[w] = incl;
    __syncthreads();
    int off = 0;
    for (int k = 0; k < w; ++k) off += ws[k];
    int excl = off + incl - v;
    int node = (r << 8) + t;
    if (node <= nnodes) offs[node] = rb + excl;
    cur[t] = rb + excl;
    __syncthreads();
    for (int e = rb + t; e < re; e += 256) {
        unsigned p = ebuf[e];
        int s = atomicAdd(&cur[p >> 16], 1);
        ssrc[s] = (int)(p & 0xFFFFu);
    }
}

// ---------------- MFMA GEMM: Y = bf16(X @ W + b) ---------------------------
// BM=64 rows/block, 4 waves, wave w: rows [16w,16w+16). A staged in LDS with
// kb-slot XOR swizzle; B from pre-transposed Wt[col][k] (L2-resident).
__launch_bounds__(256)
__global__ void gemm1_kernel(const float* __restrict__ X, const ushort* __restrict__ Wt,
                             const float* __restrict__ Bb, ushort* __restrict__ Y, int nrows) {
    __shared__ uint4 As[1024];        // 64 rows x 16 kb-slots (8 bf16 each)
    const int t = threadIdx.x;
    const int rowBase = blockIdx.x * 64;
#pragma unroll
    for (int i = 0; i < 4; ++i) {
        int s = i * 256 + t;
        int r = s >> 4, kb = s & 15;
        int grow = rowBase + r;
        float4 f0 = make_float4(0.f,0.f,0.f,0.f), f1 = f0;
        if (grow < nrows) {
            const float4* xp = (const float4*)(X + (size_t)grow * 128 + kb * 8);
            f0 = xp[0]; f1 = xp[1];
        }
        uint4 u;
        u.x = f2bf_pack(f0.x, f0.y); u.y = f2bf_pack(f0.z, f0.w);
        u.z = f2bf_pack(f1.x, f1.y); u.w = f2bf_pack(f1.z, f1.w);
        As[r * 16 + (kb ^ (r & 15))] = u;
    }
    __syncthreads();
    const int lane = t & 63, w = t >> 6;
    const int row = w * 16 + (lane & 15);
    const int lg = lane >> 4;
    f32x4 acc[8];
#pragma unroll
    for (int tc = 0; tc < 8; ++tc) acc[tc] = (f32x4){0.f, 0.f, 0.f, 0.f};
    const uint4* Wv = (const uint4*)Wt;
#pragma unroll
    for (int ks = 0; ks < 4; ++ks) {
        int kb = ks * 4 + lg;
        bf16x8 a = *(const bf16x8*)&As[row * 16 + (kb ^ (row & 15))];
#pragma unroll
        for (int tc = 0; tc < 8; ++tc) {
            int col = tc * 16 + (lane & 15);
            bf16x8 b = *(const bf16x8*)&Wv[col * 16 + kb];
            acc[tc] = __builtin_amdgcn_mfma_f32_16x16x32_bf16(a, b, acc[tc], 0, 0, 0);
        }
    }
#pragma unroll
    for (int tc = 0; tc < 8; ++tc) {
        int col = tc * 16 + (lane & 15);
        float bias = Bb[col];
#pragma unroll
        for (int e = 0; e < 4; ++e) {
            int grow = rowBase + w * 16 + lg * 4 + e;
            if (grow < nrows) Y[(size_t)grow * 128 + col] = f2bf(acc[tc][e] + bias);
        }
    }
}

__launch_bounds__(256)
__global__ void gemm2_kernel(const ushort* __restrict__ Hb, const ushort* __restrict__ Wt,
                             const float* __restrict__ Bb, ushort* __restrict__ Y, int nrows) {
    __shared__ uint4 As[1024];
    const int t = threadIdx.x;
    const int rowBase = blockIdx.x * 64;
    const uint4* Hv = (const uint4*)Hb;
#pragma unroll
    for (int i = 0; i < 4; ++i) {
        int s = i * 256 + t;
        int r = s >> 4, kb = s & 15;
        int grow = rowBase + r;
        uint4 u = make_uint4(0u, 0u, 0u, 0u);
        if (grow < nrows) u = Hv[(size_t)grow * 16 + kb];
        As[r * 16 + (kb ^ (r & 15))] = u;
    }
    __syncthreads();
    const int lane = t & 63, w = t >> 6;
    const int row = w * 16 + (lane & 15);
    const int lg = lane >> 4;
    f32x4 acc[4];
#pragma unroll
    for (int tc = 0; tc < 4; ++tc) acc[tc] = (f32x4){0.f, 0.f, 0.f, 0.f};
    const uint4* Wv = (const uint4*)Wt;
#pragma unroll
    for (int ks = 0; ks < 4; ++ks) {
        int kb = ks * 4 + lg;
        bf16x8 a = *(const bf16x8*)&As[row * 16 + (kb ^ (row & 15))];
#pragma unroll
        for (int tc = 0; tc < 4; ++tc) {
            int col = tc * 16 + (lane & 15);
            bf16x8 b = *(const bf16x8*)&Wv[col * 16 + kb];
            acc[tc] = __builtin_amdgcn_mfma_f32_16x16x32_bf16(a, b, acc[tc], 0, 0, 0);
        }
    }
#pragma unroll
    for (int tc = 0; tc < 4; ++tc) {
        int col = tc * 16 + (lane & 15);
        float bias = Bb[col];
#pragma unroll
        for (int e = 0; e < 4; ++e) {
            int grow = rowBase + w * 16 + lg * 4 + e;
            if (grow < nrows) Y[(size_t)grow * 64 + col] = f2bf(acc[tc][e] + bias);
        }
    }
}

// ---------------- aggregation ----------------------------------------------
// agg1: D=128, one wave/node, uint (2 bf16) per lane, unroll 8, bf16 h out.
__launch_bounds__(256)
__global__ void agg1_kernel(const unsigned* __restrict__ Yu, const int* __restrict__ offs,
                            const int* __restrict__ ssrc, const float* __restrict__ curv,
                            unsigned* __restrict__ Hb, int nnodes) {
    const int wid = threadIdx.x >> 6, lane = threadIdx.x & 63;
    const int node = blockIdx.x * 4 + wid;
    if (node >= nnodes) return;
    unsigned u = Yu[(size_t)node * 64 + lane];
    float a0 = bflo(u), a1 = bfhi(u);
    float b0 = 0.f, b1 = 0.f, c0 = 0.f, c1 = 0.f, d0 = 0.f, d1 = 0.f;
    const int s0 = offs[node], s1 = offs[node + 1];
    int j = s0;
    for (; j + 8 <= s1; j += 8) {
        int sA = ssrc[j], sB = ssrc[j+1], sC = ssrc[j+2], sD = ssrc[j+3];
        int sE = ssrc[j+4], sF = ssrc[j+5], sG = ssrc[j+6], sH = ssrc[j+7];
        unsigned uA = Yu[(size_t)sA * 64 + lane];
        unsigned uB = Yu[(size_t)sB * 64 + lane];
        unsigned uC = Yu[(size_t)sC * 64 + lane];
        unsigned uD = Yu[(size_t)sD * 64 + lane];
        unsigned uE = Yu[(size_t)sE * 64 + lane];
        unsigned uF = Yu[(size_t)sF * 64 + lane];
        unsigned uG = Yu[(size_t)sG * 64 + lane];
        unsigned uH = Yu[(size_t)sH * 64 + lane];
        a0 += bflo(uA) + bflo(uB); a1 += bfhi(uA) + bfhi(uB);
        b0 += bflo(uC) + bflo(uD); b1 += bfhi(uC) + bfhi(uD);
        c0 += bflo(uE) + bflo(uF); c1 += bfhi(uE) + bfhi(uF);
        d0 += bflo(uG) + bflo(uH); d1 += bfhi(uG) + bfhi(uH);
    }
    for (; j < s1; ++j) {
        unsigned uA = Yu[(size_t)ssrc[j] * 64 + lane];
        a0 += bflo(uA); a1 += bfhi(uA);
    }
    a0 += b0 + c0 + d0; a1 += b1 + c1 + d1;
    const float sc = -fabsf(curv[0]);
    a0 = fmaxf(a0 * sc, 0.f); a1 = fmaxf(a1 * sc, 0.f);
    Hb[(size_t)node * 64 + lane] = f2bf_pack(a0, a1);
}

// agg2: D=64, one wave/node, 2 edges per wave-iter (half-wave per edge),
// log_softmax over 64 cols held as 32 lanes x 2.
__launch_bounds__(256)
__global__ void agg2_kernel(const unsigned* __restrict__ Yu, const int* __restrict__ offs,
                            const int* __restrict__ ssrc, const float* __restrict__ curv,
                            float* __restrict__ out, int nnodes) {
    const int wid = threadIdx.x >> 6, lane = threadIdx.x & 63;
    const int node = blockIdx.x * 4 + wid;
    if (node >= nnodes) return;
    const int half = lane >> 5, l2 = lane & 31;
    float a0 = 0.f, a1 = 0.f, b0 = 0.f, b1 = 0.f;
    if (half == 0) {
        unsigned u = Yu[(size_t)node * 32 + l2];
        a0 = bflo(u); a1 = bfhi(u);
    }
    const int s0 = offs[node], s1 = offs[node + 1];
    int j = s0;
    for (; j + 16 <= s1; j += 16) {
#pragma unroll
        for (int i = 0; i < 8; ++i) {
            int s = ssrc[j + 2 * i + half];
            unsigned u = Yu[(size_t)s * 32 + l2];
            if (i & 1) { b0 += bflo(u); b1 += bfhi(u); }
            else       { a0 += bflo(u); a1 += bfhi(u); }
        }
    }
    for (; j < s1; j += 2) {
        int idx = j + half;
        if (idx < s1) {
            unsigned u = Yu[(size_t)ssrc[idx] * 32 + l2];
            a0 += bflo(u); a1 += bfhi(u);
        }
    }
    a0 += b0; a1 += b1;
    a0 += __shfl_xor(a0, 32);
    a1 += __shfl_xor(a1, 32);
    const float sc = -fabsf(curv[0]);
    a0 *= sc; a1 *= sc;
    float m = fmaxf(a0, a1);
#pragma unroll
    for (int d = 16; d; d >>= 1) m = fmaxf(m, __shfl_xor(m, d));
    float s = expf(a0 - m) + expf(a1 - m);
#pragma unroll
    for (int d = 16; d; d >>= 1) s += __shfl_xor(s, d);
    float ls = logf(s);
    if (half == 0)
        *(float2*)(out + (size_t)node * 64 + 2 * l2) = make_float2(a0 - m - ls, a1 - m - ls);
}

// ---------------------------------------------------------------------------
extern "C" void kernel_launch(void* const* d_in, const int* in_sizes, int n_in,
                              void* d_out, int out_size, void* d_ws, size_t ws_size,
                              hipStream_t stream) {
    const float* x     = (const float*)d_in[0];
    const int*   ei    = (const int*)d_in[1];
    const float* W1    = (const float*)d_in[2];
    const float* b1    = (const float*)d_in[3];
    const float* curv1 = (const float*)d_in[6];
    const float* W2    = (const float*)d_in[7];
    const float* b2    = (const float*)d_in[8];
    const float* curv2 = (const float*)d_in[11];
    float* out = (float*)d_out;

    const int N = 50000;
    const int E = in_sizes[1] / 2;     // 800000
    const int* src = ei;
    const int* dst = ei + E;
    const int NBE = (E + 4095) / 4096; // 196

    char* ws = (char*)d_ws;
    const size_t MB = 1024u * 1024u;
    ushort*   Y1b    = (ushort*)(ws);                 // bf16 [N,128] = 12.8 MB (reused as Y2b)
    ushort*   Hb     = (ushort*)(ws + 13 * MB);       // bf16 [N,128] = 12.8 MB
    unsigned* ebuf   = (unsigned*)(ws + 26 * MB);     // 3.2 MB
    int*      ssrc   = (int*)(ws + 30 * MB);          // 3.2 MB
    int*      offs   = (int*)(ws + 34 * MB);          // N+1
    int*      rangeCnt    = (int*)(ws + 35 * MB);
    int*      rangeBase   = (int*)(ws + 35 * MB + 4096);
    int*      rangeCursor = (int*)(ws + 35 * MB + 8192);
    ushort*   Wt1    = (ushort*)(ws + 35 * MB + 16384);   // 32 KB
    ushort*   Wt2    = (ushort*)(ws + 35 * MB + 65536 + 16384); // 16 KB

    hipMemsetAsync(rangeCnt, 0, NRANGE * sizeof(int), stream);
    prep_kernel<<<dim3(96), dim3(256), 0, stream>>>(W1, W2, Wt1, Wt2);

    histA_kernel<<<dim3(NBE), dim3(256), 0, stream>>>(dst, rangeCnt, E);
    scanA_kernel<<<dim3(1), dim3(256), 0, stream>>>(rangeCnt, rangeBase, rangeCursor);
    scatterA_kernel<<<dim3(NBE), dim3(256), 0, stream>>>(src, dst, rangeCursor, ebuf, E);
    sortB_kernel<<<dim3(NRANGE), dim3(256), 0, stream>>>(ebuf, rangeBase, offs, ssrc, N);

    gemm1_kernel<<<dim3((N + 63) / 64), dim3(256), 0, stream>>>(x, Wt1, b1, Y1b, N);
    agg1_kernel<<<dim3((N + 3) / 4), dim3(256), 0, stream>>>((const unsigned*)Y1b, offs, ssrc, curv1, (unsigned*)Hb, N);

    gemm2_kernel<<<dim3((N + 63) / 64), dim3(256), 0, stream>>>(Hb, Wt2, b2, Y1b, N);
    agg2_kernel<<<dim3((N + 3) / 4), dim3(256), 0, stream>>>((const unsigned*)Y1b, offs, ssrc, curv2, out, N);
}